// Round 7
// baseline (410.514 us; speedup 1.0000x reference)
//
#include <hip/hip_runtime.h>
#include <hip/hip_cooperative_groups.h>
#include <math.h>

namespace cg = cooperative_groups;

typedef unsigned short u16;
typedef __attribute__((ext_vector_type(8))) short short8v;   // 8 bf16
typedef __attribute__((ext_vector_type(4))) float f32x4;

constexpr int B_   = 4;
constexpr int L_   = 8192;
constexpr int D_   = 128;
constexpr int N_   = 32;
constexpr int BL   = B_ * L_;         // 32768 rows
constexpr int CH   = 16;              // chunk rows
constexpr int NC   = L_ / CH;         // 512 chunks per batch
constexpr int ROWS = 128;             // rows per mega block
constexpr int NBLK = BL / ROWS;       // 256 blocks = 1/CU

// round-to-nearest-even f32 -> bf16
__device__ inline unsigned bfr(float x) {
    unsigned u = __float_as_uint(x);
    return (u + 0x7fffu + ((u >> 16) & 1u)) >> 16;
}
__device__ inline unsigned pkbf(float a, float b) { return bfr(a) | (bfr(b) << 16); }
__device__ inline float b2f(u16 h) { return __uint_as_float(((unsigned)h) << 16); }

// ---------------------------------------------------------------------------
// prep_weff: W_eff[k][d] = sum_j Wx[k, j<128] * Wdt[j][d]  -> Wt0[d][k] bf16.
// ---------------------------------------------------------------------------
__global__ __launch_bounds__(512) void prep_weff(
    const float* __restrict__ Wx, const float* __restrict__ Wdt,
    u16* __restrict__ Wt0)
{
    __shared__ float wd[128 * 128];
    const int tid = threadIdx.x;
    #pragma unroll
    for (int j = 0; j < 8; ++j) {
        const int g = tid + j * 512;
        *reinterpret_cast<float4*>(&wd[g * 4]) =
            *reinterpret_cast<const float4*>(&Wdt[(size_t)g * 4]);
    }
    __syncthreads();
    const int k = blockIdx.x * 4 + (tid >> 7);
    const int d = tid & 127;
    float s = 0.f;
    #pragma unroll 8
    for (int j = 0; j < 128; ++j)
        s = fmaf(Wx[(size_t)k * 192 + j], wd[j * 128 + d], s);
    Wt0[d * 128 + k] = (u16)bfr(s);
}

// ---------------------------------------------------------------------------
// prep_rest: y=0: W_x B/C cols^T -> Wt0 rows 128..191; y=1: W_f^T -> Wt2;
// y=2..4: conv taps^T -> Wtc; y=5: negAT[n][d]; y=6: amax[d].
// ---------------------------------------------------------------------------
__global__ __launch_bounds__(256) void prep_rest(
    const float* __restrict__ Wx, const float* __restrict__ Wf,
    const float* __restrict__ Wconv, const float* __restrict__ A_log,
    u16* __restrict__ Wt0, u16* __restrict__ Wt2, u16* __restrict__ Wtc,
    float* __restrict__ negAT, float* __restrict__ amax)
{
    const int which = blockIdx.y;
    const int t = blockIdx.x * 256 + threadIdx.x;
    constexpr float L2E = 1.4426950408889634f;
    if (which == 0) {
        if (t >= 64 * 128) return;
        const int n = t >> 7, k = t & 127;
        Wt0[(128 + n) * 128 + k] = (u16)bfr(Wx[(size_t)k * 192 + 128 + n]);
    } else if (which == 1) {
        if (t >= 128 * 128) return;
        const int n = t >> 7, k = t & 127;
        Wt2[n * 128 + k] = (u16)bfr(Wf[(size_t)k * 128 + n]);
    } else if (which <= 4) {
        if (t >= 128 * 128) return;
        const int w = which - 2;
        const int n = t >> 7, k = t & 127;
        Wtc[((size_t)w * 128 + n) * 128 + k] = (u16)bfr(Wconv[((size_t)w * 128 + k) * 128 + n]);
    } else if (which == 5) {
        if (t >= 128 * 32) return;
        const int d = t >> 5, n = t & 31;
        negAT[n * 128 + d] = -expf(A_log[d * 32 + n]) * L2E;
    } else {
        if (t >= 128) return;
        float m = -1e30f;
        for (int n = 0; n < 32; ++n)
            m = fmaxf(m, -expf(A_log[t * 32 + n]) * L2E);
        amax[t] = m;
    }
}

// ---------------------------------------------------------------------------
// mega (cooperative, grid=256 x 512thr, 1 block/CU, 128KB LDS):
//  P1: gemm x@[W_eff|W_B|W_C] (weights from L2) -> delta_s/bc_s LDS,
//      chunk sums -> part (global)
//  P2: grid-wide exclusive prefix over part
//  P3: scan: walk delta_s for Sloc; h = dv*hv*(1+Dp)*sum bc*exp2(S*negA)
//      with underflow skip -> h_out (d_out) + h_s (bf16 LDS)
//  P4: ssm = relu(h_s @ W_f + b_f) -> ssm_s LDS (+ last 2 rows -> global)
//  P5: conv3 MFMA + relu + fused multiply -> out
// ---------------------------------------------------------------------------
__global__ __launch_bounds__(512, 2) void mega(
    const float* __restrict__ x, const float* __restrict__ hprev,
    const u16* __restrict__ Wt0, const u16* __restrict__ Wt2,
    const u16* __restrict__ Wtc,
    const float* __restrict__ b_dt, const float* __restrict__ b_f,
    const float* __restrict__ cbias,
    const float* __restrict__ negAT, const float* __restrict__ amax,
    const float* __restrict__ Dp,
    float* __restrict__ part, u16* __restrict__ ssm,
    float* __restrict__ h_out, float* __restrict__ fused)
{
    __shared__ __align__(16) char smem[131072];
    float* delta_s = (float*)smem;                 // [128][128] f32, 64KB
    float* bc_s    = (float*)(smem + 65536);       // [128][32]  f32, 16KB
    float* at_s    = (float*)(smem + 81920);       // [32][128]  f32, 16KB
    u16*   h_s     = (u16*)(smem + 98304);         // [128][128] bf16 swz, 32KB
    u16*   ssm_s   = (u16*)smem;                   // [130][128] bf16 swz (aliases delta_s)
    __shared__ float wsum[8];

    cg::grid_group grid = cg::this_grid();
    const int tid = threadIdx.x;
    const int bid = blockIdx.x;
    const int R0 = bid * ROWS;
    const int w = tid >> 6, lane = tid & 63;
    const int lr = lane & 15, kg = lane >> 4;

    // ================= P1: gemm1 =================
    {
        const int arow = R0 + w * 16 + lr;
        float4 av[4][2];
        #pragma unroll
        for (int ks = 0; ks < 4; ++ks) {
            const float* src = &x[(size_t)arow * 128 + ks * 32 + kg * 8];
            av[ks][0] = *reinterpret_cast<const float4*>(src);
            av[ks][1] = *reinterpret_cast<const float4*>(src + 4);
        }
        f32x4 acc[12] = {};
        #pragma unroll
        for (int ks = 0; ks < 4; ++ks) {
            uint4 ap;
            ap.x = pkbf(av[ks][0].x, av[ks][0].y);
            ap.y = pkbf(av[ks][0].z, av[ks][0].w);
            ap.z = pkbf(av[ks][1].x, av[ks][1].y);
            ap.w = pkbf(av[ks][1].z, av[ks][1].w);
            const short8v af = *reinterpret_cast<const short8v*>(&ap);
            const int kb = ks * 32 + kg * 8;
            #pragma unroll
            for (int nf = 0; nf < 12; ++nf) {
                const int n = nf * 16 + lr;
                const short8v bf = *reinterpret_cast<const short8v*>(
                    &Wt0[(size_t)n * 128 + kb]);
                acc[nf] = __builtin_amdgcn_mfma_f32_16x16x32_bf16(af, bf, acc[nf], 0, 0, 0);
            }
        }
        // epilogue: softplus -> delta_s; chunk sums -> part; bc -> bc_s
        const int orowl = w * 16;                           // local chunk base
        const size_t chunkb = (size_t)((R0 + orowl) >> 4) * 128;
        #pragma unroll
        for (int nf = 0; nf < 8; ++nf) {
            const int col = nf * 16 + lr;
            const float bb = b_dt[col];
            float v[4];
            #pragma unroll
            for (int q = 0; q < 4; ++q) {
                const float t = acc[nf][q] + bb;
                v[q] = fmaxf(t, 0.f) + log1pf(expf(-fabsf(t)));
            }
            const float g4 = v[0] + v[1] + v[2] + v[3];
            const float g0 = __shfl(g4, lr, 64);
            const float g1 = __shfl(g4, lr + 16, 64);
            const float g2 = __shfl(g4, lr + 32, 64);
            const float g3 = __shfl(g4, lr + 48, 64);
            const int rl = orowl + kg * 4;
            delta_s[(rl + 0) * 128 + col] = v[0];
            delta_s[(rl + 1) * 128 + col] = v[1];
            delta_s[(rl + 2) * 128 + col] = v[2];
            delta_s[(rl + 3) * 128 + col] = v[3];
            if (kg == 0) part[chunkb + col] = g0 + g1 + g2 + g3;
        }
        #pragma unroll
        for (int h2 = 0; h2 < 2; ++h2)
            #pragma unroll
            for (int q = 0; q < 4; ++q)
                bc_s[(orowl + kg * 4 + q) * 32 + h2 * 16 + lr] =
                    acc[8 + h2][q] * acc[10 + h2][q];
    }
    __threadfence();
    grid.sync();

    // ================= P2: exclusive prefix over part =================
    #pragma unroll 1
    for (int si = 0; si < 2; ++si) {
        const int s = bid * 2 + si;                 // series (b,d)
        const int b = s >> 7, d = s & 127;
        const size_t idx = ((size_t)b * NC + tid) * 128 + d;
        const float v = part[idx];
        float sc = v;
        #pragma unroll
        for (int off = 1; off < 64; off <<= 1) {
            const float t = __shfl_up(sc, off, 64);
            if (lane >= off) sc += t;
        }
        if (lane == 63) wsum[w] = sc;
        __syncthreads();
        float add = 0.f;
        #pragma unroll
        for (int i2 = 0; i2 < 8; ++i2)
            if (i2 < w) add += wsum[i2];
        part[idx] = sc + add - v;                   // exclusive
        __syncthreads();
    }
    __threadfence();
    grid.sync();

    // ================= P3: scan =================
    {
        #pragma unroll
        for (int j = 0; j < 2; ++j) {               // stage negAT 16KB
            const int g = tid + j * 512;
            reinterpret_cast<float4*>(at_s)[g] =
                reinterpret_cast<const float4*>(negAT)[g];
        }
        __syncthreads();
        const int d = tid & 127, r0 = tid >> 7;
        const float dp1 = 1.f + Dp[d];
        const float am = amax[d];
        #pragma unroll 1
        for (int cc = 0; cc < 8; ++cc) {
            float s = part[(size_t)((R0 >> 4) + cc) * 128 + d];
            float sv[4];
            #pragma unroll
            for (int i = 0; i < 16; ++i) {
                if ((i & 3) == r0) sv[i >> 2] = s;
                s += delta_s[(cc * 16 + i) * 128 + d];
            }
            #pragma unroll 1
            for (int k = 0; k < 4; ++k) {
                const int row = cc * 16 + k * 4 + r0;
                const size_t rb = (size_t)(R0 + row) * 128 + d;
                const float S = sv[k];
                float h = 0.f;
                if (__any(S * am >= -80.f)) {       // underflow skip
                    const float dv = delta_s[row * 128 + d];
                    const float hv = hprev[rb];
                    float p0 = 0.f, p1 = 0.f, p2 = 0.f, p3 = 0.f;
                    #pragma unroll
                    for (int n4 = 0; n4 < 8; ++n4) {
                        const float4 b4 = *reinterpret_cast<const float4*>(
                            &bc_s[row * 32 + n4 * 4]);
                        p0 = fmaf(b4.x, exp2f(S * at_s[(n4 * 4 + 0) * 128 + d]), p0);
                        p1 = fmaf(b4.y, exp2f(S * at_s[(n4 * 4 + 1) * 128 + d]), p1);
                        p2 = fmaf(b4.z, exp2f(S * at_s[(n4 * 4 + 2) * 128 + d]), p2);
                        p3 = fmaf(b4.w, exp2f(S * at_s[(n4 * 4 + 3) * 128 + d]), p3);
                    }
                    h = dv * hv * ((p0 + p1) + (p2 + p3)) * dp1;
                }
                h_out[rb] = h;
                h_s[row * 128 + (d ^ ((row & 7) << 3))] = (u16)bfr(h);
            }
        }
    }
    __syncthreads();

    // ================= P4: ssm = relu(h @ W_f + b_f) =================
    {
        f32x4 acc[8] = {};
        #pragma unroll
        for (int ks = 0; ks < 4; ++ks) {
            const int k8 = ks * 32 + kg * 8;
            const int row = w * 16 + lr;
            const short8v af = *reinterpret_cast<const short8v*>(
                &h_s[row * 128 + (k8 ^ ((row & 7) << 3))]);
            #pragma unroll
            for (int nf = 0; nf < 8; ++nf) {
                const int col = nf * 16 + lr;
                const short8v bf = *reinterpret_cast<const short8v*>(
                    &Wt2[(size_t)col * 128 + k8]);
                acc[nf] = __builtin_amdgcn_mfma_f32_16x16x32_bf16(af, bf, acc[nf], 0, 0, 0);
            }
        }
        #pragma unroll
        for (int nf = 0; nf < 8; ++nf) {
            const int col = nf * 16 + lr;
            const float bbv = b_f[col];
            #pragma unroll
            for (int q = 0; q < 4; ++q) {
                const int row = w * 16 + kg * 4 + q;
                const u16 sv16 = (u16)bfr(fmaxf(acc[nf][q] + bbv, 0.f));
                const int ri = row + 2;
                ssm_s[ri * 128 + (col ^ ((ri & 7) << 3))] = sv16;
                if (row >= ROWS - 2)                 // halo for next block only
                    ssm[(size_t)(R0 + row) * 128 + col] = sv16;
            }
        }
    }
    __threadfence();
    grid.sync();

    // ================= P5: conv3 + fuse =================
    {
        if (tid < 32) {                              // halo rows 0,1
            const int i = tid >> 4, k8 = (tid & 15) * 8;
            uint4 p = make_uint4(0, 0, 0, 0);
            if ((bid & 63) != 0) {                   // not batch start
                const int gr = R0 - 2 + i;
                p = *reinterpret_cast<const uint4*>(&ssm[(size_t)gr * 128 + k8]);
            }
            *reinterpret_cast<uint4*>(&ssm_s[i * 128 + (k8 ^ ((i & 7) << 3))]) = p;
        }
        __syncthreads();

        f32x4 acc[8] = {};
        #pragma unroll
        for (int ks = 0; ks < 4; ++ks) {
            const int k8 = ks * 32 + kg * 8;
            short8v af[3];
            #pragma unroll
            for (int t = 0; t < 3; ++t) {
                const int ri = w * 16 + lr + t;
                af[t] = *reinterpret_cast<const short8v*>(
                    &ssm_s[ri * 128 + (k8 ^ ((ri & 7) << 3))]);
            }
            #pragma unroll
            for (int nf = 0; nf < 8; ++nf) {
                const int col = nf * 16 + lr;
                #pragma unroll
                for (int t = 0; t < 3; ++t) {
                    const short8v bf = *reinterpret_cast<const short8v*>(
                        &Wtc[((size_t)t * 128 + col) * 128 + k8]);
                    acc[nf] = __builtin_amdgcn_mfma_f32_16x16x32_bf16(af[t], bf, acc[nf], 0, 0, 0);
                }
            }
        }
        #pragma unroll
        for (int nf = 0; nf < 8; ++nf) {
            const int col = nf * 16 + lr;
            const float cb = cbias[col];
            #pragma unroll
            for (int q = 0; q < 4; ++q) {
                const int ro = w * 16 + kg * 4 + q;
                const int ri = ro + 2;
                const u16 sh = ssm_s[ri * 128 + (col ^ ((ri & 7) << 3))];
                fused[(size_t)(R0 + ro) * 128 + col] =
                    b2f(sh) * fmaxf(acc[nf][q] + cb, 0.f);
            }
        }
    }
}

// ---------------------------------------------------------------------------
extern "C" void kernel_launch(void* const* d_in, const int* in_sizes, int n_in,
                              void* d_out, int out_size, void* d_ws, size_t ws_size,
                              hipStream_t stream)
{
    const float* x      = (const float*)d_in[0];
    const float* hprev  = (const float*)d_in[1];
    const float* A_log  = (const float*)d_in[2];
    const float* Dp     = (const float*)d_in[3];
    const float* W_x    = (const float*)d_in[4];
    const float* W_dt   = (const float*)d_in[5];
    const float* b_dt   = (const float*)d_in[6];
    const float* conv_w = (const float*)d_in[7];
    const float* conv_b = (const float*)d_in[8];
    const float* W_f    = (const float*)d_in[9];
    const float* b_f    = (const float*)d_in[10];

    float* out   = (float*)d_out;                       // fused_output
    float* h_out = out + (size_t)BL * D_;               // h_t

    char* ws = (char*)d_ws;
    float* part  = (float*)ws;                  ws += (size_t)B_ * NC * 128 * 4;
    float* negAT = (float*)ws;                  ws += (size_t)N_ * 128 * 4;
    float* amaxb = (float*)ws;                  ws += (size_t)128 * 4;
    u16*   Wt0   = (u16*)ws;                    ws += (size_t)192 * 128 * 2;
    u16*   Wt2   = (u16*)ws;                    ws += (size_t)128 * 128 * 2;
    u16*   Wtc   = (u16*)ws;                    ws += (size_t)3 * 128 * 128 * 2;
    u16*   ssm   = (u16*)ws;

    prep_weff<<<dim3(32), dim3(512), 0, stream>>>(W_x, W_dt, Wt0);
    prep_rest<<<dim3(64, 7), dim3(256), 0, stream>>>(
        W_x, W_f, conv_w, A_log, Wt0, Wt2, Wtc, negAT, amaxb);

    void* kargs[] = {
        (void*)&x, (void*)&hprev, (void*)&Wt0, (void*)&Wt2, (void*)&Wtc,
        (void*)&b_dt, (void*)&b_f, (void*)&conv_b, (void*)&negAT,
        (void*)&amaxb, (void*)&Dp, (void*)&part, (void*)&ssm,
        (void*)&h_out, (void*)&out
    };
    hipLaunchCooperativeKernel((const void*)mega, dim3(NBLK), dim3(512),
                               kargs, 0, stream);
}

// Round 8
// 168.945 us; speedup vs baseline: 2.4299x; 2.4299x over previous
//
#include <hip/hip_runtime.h>
#include <math.h>

typedef unsigned short u16;
typedef __attribute__((ext_vector_type(8))) short short8v;   // 8 bf16
typedef __attribute__((ext_vector_type(4))) float f32x4;

constexpr int B_  = 4;
constexpr int L_  = 8192;
constexpr int D_  = 128;
constexpr int N_  = 32;
constexpr int BL  = B_ * L_;          // 32768 rows
constexpr int CH  = 16;               // chunk rows (one gemm1 wave)
constexpr int NC  = L_ / CH;          // 512 chunks per batch
constexpr int SCH = 32;               // scan_main rows per block
constexpr int SNC = L_ / SCH;         // 256

// round-to-nearest-even f32 -> bf16
__device__ inline unsigned bfr(float x) {
    unsigned u = __float_as_uint(x);
    return (u + 0x7fffu + ((u >> 16) & 1u)) >> 16;
}
__device__ inline unsigned pkbf(float a, float b) { return bfr(a) | (bfr(b) << 16); }
__device__ inline float b2f(u16 h) { return __uint_as_float(((unsigned)h) << 16); }

// ---------------------------------------------------------------------------
// prep_weff: W_eff[k][d] = sum_j Wx[k, j<128] * Wdt[j][d]  -> Wt0[d][k] bf16.
// ---------------------------------------------------------------------------
__global__ __launch_bounds__(512) void prep_weff(
    const float* __restrict__ Wx, const float* __restrict__ Wdt,
    u16* __restrict__ Wt0)
{
    __shared__ float wd[128 * 128];
    const int tid = threadIdx.x;
    #pragma unroll
    for (int j = 0; j < 8; ++j) {
        const int g = tid + j * 512;
        *reinterpret_cast<float4*>(&wd[g * 4]) =
            *reinterpret_cast<const float4*>(&Wdt[(size_t)g * 4]);
    }
    __syncthreads();
    const int k = blockIdx.x * 4 + (tid >> 7);
    const int d = tid & 127;
    float s = 0.f;
    #pragma unroll 8
    for (int j = 0; j < 128; ++j)
        s = fmaf(Wx[(size_t)k * 192 + j], wd[j * 128 + d], s);
    Wt0[d * 128 + k] = (u16)bfr(s);
}

// ---------------------------------------------------------------------------
// prep_rest: y=0: W_x B/C cols^T -> Wt0 rows 128..191; y=1: W_f^T -> Wt2;
// y=2..4: conv taps^T -> Wtc; y=5: negAT[n][d]; y=6: amax[d].
// ---------------------------------------------------------------------------
__global__ __launch_bounds__(256) void prep_rest(
    const float* __restrict__ Wx, const float* __restrict__ Wf,
    const float* __restrict__ Wconv, const float* __restrict__ A_log,
    u16* __restrict__ Wt0, u16* __restrict__ Wt2, u16* __restrict__ Wtc,
    float* __restrict__ negAT, float* __restrict__ amax)
{
    const int which = blockIdx.y;
    const int t = blockIdx.x * 256 + threadIdx.x;
    constexpr float L2E = 1.4426950408889634f;
    if (which == 0) {
        if (t >= 64 * 128) return;
        const int n = t >> 7, k = t & 127;
        Wt0[(128 + n) * 128 + k] = (u16)bfr(Wx[(size_t)k * 192 + 128 + n]);
    } else if (which == 1) {
        if (t >= 128 * 128) return;
        const int n = t >> 7, k = t & 127;
        Wt2[n * 128 + k] = (u16)bfr(Wf[(size_t)k * 128 + n]);
    } else if (which <= 4) {
        if (t >= 128 * 128) return;
        const int w = which - 2;
        const int n = t >> 7, k = t & 127;
        Wtc[((size_t)w * 128 + n) * 128 + k] = (u16)bfr(Wconv[((size_t)w * 128 + k) * 128 + n]);
    } else if (which == 5) {
        if (t >= 128 * 32) return;
        const int d = t >> 5, n = t & 31;
        negAT[n * 128 + d] = -expf(A_log[d * 32 + n]) * L2E;
    } else {
        if (t >= 128) return;
        float m = -1e30f;
        for (int n = 0; n < 32; ++n)
            m = fmaxf(m, -expf(A_log[t * 32 + n]) * L2E);
        amax[t] = m;
    }
}

// ---------------------------------------------------------------------------
// gemm1: x(BLx128) @ [W_eff | W_xB | W_xC](128x192), barrier-free main loop.
// 256 blocks x 512 thr x 128 rows (weights staged ONCE per block, 1 blk/CU).
// A-frags straight from global f32. Epilogue: softplus -> delta (f32);
// chunk sums -> part_t[b][d][c] (transposed); bc = B*C.  NO Sloc (scan
// reconstructs it from delta LDS walk).
// ---------------------------------------------------------------------------
__global__ __launch_bounds__(512) void gemm1(
    const float* __restrict__ x, const u16* __restrict__ Wt0,
    const float* __restrict__ b_dt,
    float* __restrict__ delta, float* __restrict__ bc,
    float* __restrict__ part)
{
    __shared__ __align__(16) u16 Blds[192 * 128];   // 48 KB, swizzled

    const int tid = threadIdx.x;
    const int R0 = blockIdx.x * 128;

    #pragma unroll
    for (int j = 0; j < 6; ++j) {   // 192 rows x 16 uint4 groups = 3072
        const int g = tid + j * 512;
        const int n = g >> 4, k8 = (g & 15) * 8;
        const uint4 p = *reinterpret_cast<const uint4*>(&Wt0[(size_t)n * 128 + k8]);
        *reinterpret_cast<uint4*>(&Blds[n * 128 + (k8 ^ ((n & 7) << 3))]) = p;
    }

    const int w = tid >> 6, lane = tid & 63;
    const int lr = lane & 15, kg = lane >> 4;
    const int arow = R0 + w * 16 + lr;

    float4 av[4][2];
    #pragma unroll
    for (int ks = 0; ks < 4; ++ks) {
        const float* src = &x[(size_t)arow * 128 + ks * 32 + kg * 8];
        av[ks][0] = *reinterpret_cast<const float4*>(src);
        av[ks][1] = *reinterpret_cast<const float4*>(src + 4);
    }
    __syncthreads();

    f32x4 acc[12] = {};
    #pragma unroll
    for (int ks = 0; ks < 4; ++ks) {
        uint4 ap;
        ap.x = pkbf(av[ks][0].x, av[ks][0].y);
        ap.y = pkbf(av[ks][0].z, av[ks][0].w);
        ap.z = pkbf(av[ks][1].x, av[ks][1].y);
        ap.w = pkbf(av[ks][1].z, av[ks][1].w);
        const short8v af = *reinterpret_cast<const short8v*>(&ap);
        const int kb = ks * 32 + kg * 8;
        #pragma unroll
        for (int nf = 0; nf < 12; ++nf) {
            const int n = nf * 16 + lr;
            const short8v bf = *reinterpret_cast<const short8v*>(
                &Blds[n * 128 + (kb ^ ((n & 7) << 3))]);
            acc[nf] = __builtin_amdgcn_mfma_f32_16x16x32_bf16(af, bf, acc[nf], 0, 0, 0);
        }
    }

    // ---- epilogue ----
    const int orow = R0 + w * 16;                  // wave's 16-row chunk base
    const int bb = orow >> 13;                     // batch
    const int chk = (orow & (L_ - 1)) >> 4;        // chunk index in batch
    #pragma unroll
    for (int nf = 0; nf < 8; ++nf) {
        const int col = nf * 16 + lr;
        const float bbv = b_dt[col];
        float v[4];
        #pragma unroll
        for (int q = 0; q < 4; ++q) {
            const float t = acc[nf][q] + bbv;
            v[q] = fmaxf(t, 0.f) + log1pf(expf(-fabsf(t)));   // stable softplus
        }
        const float g4 = v[0] + v[1] + v[2] + v[3];
        const float g0 = __shfl(g4, lr, 64);
        const float g1 = __shfl(g4, lr + 16, 64);
        const float g2 = __shfl(g4, lr + 32, 64);
        const float g3 = __shfl(g4, lr + 48, 64);
        const size_t rb = (size_t)(orow + kg * 4) * 128 + col;
        delta[rb + 0 * 128] = v[0];
        delta[rb + 1 * 128] = v[1];
        delta[rb + 2 * 128] = v[2];
        delta[rb + 3 * 128] = v[3];
        if (kg == 0)
            part[((size_t)bb * 128 + col) * NC + chk] = g0 + g1 + g2 + g3;
    }
    #pragma unroll
    for (int h2 = 0; h2 < 2; ++h2)
        #pragma unroll
        for (int q = 0; q < 4; ++q)
            bc[(size_t)(orow + kg * 4 + q) * 32 + h2 * 16 + lr] =
                acc[8 + h2][q] * acc[10 + h2][q];
}

// ---------------------------------------------------------------------------
// scan_prefix: exclusive prefix over NC=512 chunks per (b,d), COALESCED:
// part layout [b][d][c]. grid (B, D), 512 threads (one per chunk).
// ---------------------------------------------------------------------------
__global__ __launch_bounds__(512) void scan_prefix(float* __restrict__ part)
{
    const int b = blockIdx.x, d = blockIdx.y;
    const int c = threadIdx.x, w = c >> 6, lane = c & 63;
    const size_t base = ((size_t)b * 128 + d) * NC;
    const float v = part[base + c];
    float s = v;
    #pragma unroll
    for (int off = 1; off < 64; off <<= 1) {
        const float t = __shfl_up(s, off, 64);
        if (lane >= off) s += t;
    }
    __shared__ float wsum[8];
    if (lane == 63) wsum[w] = s;
    __syncthreads();
    float add = 0.f;
    #pragma unroll
    for (int i = 0; i < 8; ++i)
        if (i < w) add += wsum[i];
    part[base + c] = s + add - v;   // exclusive
}

// ---------------------------------------------------------------------------
// scan_main: per 32-row tile:
//  P1: stage delta tile (16KB) + negAT (16KB) + bc tile (4KB) to LDS
//  P2: serial 32-step walk over delta_s reconstructs per-row S (no Sloc);
//      h = dv*hv*(1+Dp)*sum_n bc*exp2(S*negA), with underflow skip
//      -> h_out f32 + h_s bf16 LDS (swizzled)
//  P3: ssm = relu(h @ W_f + b_f) via MFMA -> ssm bf16 global.
// grid (SNC, B), 512 threads.
// ---------------------------------------------------------------------------
__global__ __launch_bounds__(512) void scan_main(
    const float* __restrict__ delta, const float* __restrict__ hprev,
    const float* __restrict__ bc, const float* __restrict__ negAT,
    const float* __restrict__ amax, const float* __restrict__ Dp,
    const float* __restrict__ part,
    const u16* __restrict__ Wt2, const float* __restrict__ b_f,
    float* __restrict__ h_out, u16* __restrict__ ssm)
{
    __shared__ float delta_s[SCH * 128];          // 16 KB
    __shared__ float at_s[32 * 128];              // 16 KB  negAT[n][d]
    __shared__ float bc_s[SCH * 32];              // 4 KB
    __shared__ __align__(16) u16 h_s[SCH * 128];  // 8 KB, swizzled

    const int cb = blockIdx.x, b = blockIdx.y;
    const int tid = threadIdx.x;
    const size_t rowbase = (size_t)b * L_ + (size_t)cb * SCH;

    #pragma unroll
    for (int j = 0; j < 2; ++j) {     // delta tile: 1024 float4
        const int g = tid + j * 512;
        reinterpret_cast<float4*>(delta_s)[g] =
            reinterpret_cast<const float4*>(&delta[rowbase * 128])[g];
    }
    #pragma unroll
    for (int j = 0; j < 2; ++j) {     // negAT: 1024 float4
        const int g = tid + j * 512;
        reinterpret_cast<float4*>(at_s)[g] =
            reinterpret_cast<const float4*>(negAT)[g];
    }
    if (tid < 256)                    // 32x32 bc tile
        reinterpret_cast<float4*>(bc_s)[tid] =
            reinterpret_cast<const float4*>(&bc[rowbase * 32])[tid];

    const int d = tid & 127, r0 = tid >> 7;
    const float dp1 = 1.f + Dp[d];
    const float am = amax[d];
    const size_t pb = ((size_t)b * 128 + d) * NC + (size_t)cb * 2;
    const float part0 = part[pb];
    const float part1 = part[pb + 1];
    __syncthreads();

    // reconstruct per-row exclusive S via serial walk (2 chunks of 16)
    float sv[8];
    {
        float s = part0;
        #pragma unroll
        for (int i = 0; i < 16; ++i) {
            if ((i & 3) == r0) sv[i >> 2] = s;
            s += delta_s[i * 128 + d];
        }
        s = part1;
        #pragma unroll
        for (int i = 16; i < 32; ++i) {
            if ((i & 3) == r0) sv[i >> 2] = s;
            s += delta_s[i * 128 + d];
        }
    }

    #pragma unroll 1
    for (int r = 0; r < 8; ++r) {
        const int row = r * 4 + r0;
        const size_t rb = (rowbase + row) * 128 + d;
        const float S = sv[r];
        float h = 0.f;
        if (__any(S * am >= -80.f)) {       // underflow skip
            const float dv = delta_s[row * 128 + d];
            const float hv = hprev[rb];
            float p0 = 0.f, p1 = 0.f, p2 = 0.f, p3 = 0.f;
            #pragma unroll
            for (int n4 = 0; n4 < 8; ++n4) {
                const float4 b4 = *reinterpret_cast<const float4*>(&bc_s[row * 32 + n4 * 4]);
                p0 = fmaf(b4.x, exp2f(S * at_s[(n4 * 4 + 0) * 128 + d]), p0);
                p1 = fmaf(b4.y, exp2f(S * at_s[(n4 * 4 + 1) * 128 + d]), p1);
                p2 = fmaf(b4.z, exp2f(S * at_s[(n4 * 4 + 2) * 128 + d]), p2);
                p3 = fmaf(b4.w, exp2f(S * at_s[(n4 * 4 + 3) * 128 + d]), p3);
            }
            h = dv * hv * ((p0 + p1) + (p2 + p3)) * dp1;
        }
        h_out[rb] = h;
        h_s[row * 128 + (d ^ ((row & 7) << 3))] = (u16)bfr(h);
    }
    __syncthreads();

    // P3: (32x128) @ W_f(128x128) + relu -> ssm bf16
    const int wid = tid >> 6, lane = tid & 63;
    const int lr = lane & 15, kg = lane >> 4;
    const int col = wid * 16 + lr;
    f32x4 acc[2] = {};
    #pragma unroll
    for (int ks = 0; ks < 4; ++ks) {
        const int k8 = ks * 32 + kg * 8;
        const short8v bfg = *reinterpret_cast<const short8v*>(&Wt2[(size_t)col * 128 + k8]);
        #pragma unroll
        for (int m = 0; m < 2; ++m) {
            const int row = m * 16 + lr;
            const short8v afg = *reinterpret_cast<const short8v*>(
                &h_s[row * 128 + (k8 ^ ((row & 7) << 3))]);
            acc[m] = __builtin_amdgcn_mfma_f32_16x16x32_bf16(afg, bfg, acc[m], 0, 0, 0);
        }
    }
    const float bb = b_f[col];
    #pragma unroll
    for (int m = 0; m < 2; ++m)
        #pragma unroll
        for (int q = 0; q < 4; ++q) {
            const int row = m * 16 + kg * 4 + q;
            const float v = fmaxf(acc[m][q] + bb, 0.f);
            ssm[(rowbase + row) * 128 + col] = (u16)bfr(v);
        }
}

// ---------------------------------------------------------------------------
// conv_fuse: fused = ssm * relu(causal_conv3(ssm) + conv_b)
// BM=64 (+2 halo), 512 threads = 8 waves (wm 2 x wn 4); weights from L2.
// ---------------------------------------------------------------------------
__global__ __launch_bounds__(512) void conv_fuse(
    const u16* __restrict__ ssm, const u16* __restrict__ Wtc,
    const float* __restrict__ cbias, float* __restrict__ fused)
{
    __shared__ __align__(16) u16 Alds[66 * 128];   // 16.9 KB, swizzled

    const int tid = threadIdx.x;
    const int bb = blockIdx.y;
    const int r0 = blockIdx.x * 64;
    const u16* sb = ssm + (size_t)bb * L_ * 128;

    #pragma unroll
    for (int j = 0; j < 3; ++j) {
        const int g = tid + j * 512;
        if (g < 66 * 16) {
            const int i = g >> 4, k8 = (g & 15) * 8;
            const int gr = r0 - 2 + i;
            uint4 p = make_uint4(0, 0, 0, 0);
            if (gr >= 0)
                p = *reinterpret_cast<const uint4*>(&sb[(size_t)gr * 128 + k8]);
            *reinterpret_cast<uint4*>(&Alds[i * 128 + (k8 ^ ((i & 7) << 3))]) = p;
        }
    }
    __syncthreads();

    const int wid = tid >> 6, lane = tid & 63;
    const int wm = wid >> 2, wn = wid & 3;
    const int lr = lane & 15, kg = lane >> 4;

    f32x4 acc[2][2] = {};
    #pragma unroll
    for (int ks = 0; ks < 4; ++ks) {
        const int k8 = ks * 32 + kg * 8;
        short8v af[2][3];
        #pragma unroll
        for (int m = 0; m < 2; ++m)
            #pragma unroll
            for (int w = 0; w < 3; ++w) {
                const int ri = wm * 32 + m * 16 + lr + w;
                af[m][w] = *reinterpret_cast<const short8v*>(
                    &Alds[ri * 128 + (k8 ^ ((ri & 7) << 3))]);
            }
        #pragma unroll
        for (int nf = 0; nf < 2; ++nf) {
            const int col = wn * 32 + nf * 16 + lr;
            #pragma unroll
            for (int w = 0; w < 3; ++w) {
                const short8v bfg = *reinterpret_cast<const short8v*>(
                    &Wtc[((size_t)w * 128 + col) * 128 + k8]);
                acc[0][nf] = __builtin_amdgcn_mfma_f32_16x16x32_bf16(af[0][w], bfg, acc[0][nf], 0, 0, 0);
                acc[1][nf] = __builtin_amdgcn_mfma_f32_16x16x32_bf16(af[1][w], bfg, acc[1][nf], 0, 0, 0);
            }
        }
    }

    #pragma unroll
    for (int nf = 0; nf < 2; ++nf) {
        const int col = wn * 32 + nf * 16 + lr;
        const float bb2 = cbias[col];
        #pragma unroll
        for (int m = 0; m < 2; ++m)
            #pragma unroll
            for (int q = 0; q < 4; ++q) {
                const int row = wm * 32 + m * 16 + kg * 4 + q;
                const int ri = row + 2;
                const u16 sh = Alds[ri * 128 + ((((col >> 3) ^ (ri & 7)) << 3)) + (col & 7)];
                const float cv = fmaxf(acc[m][nf][q] + bb2, 0.f);
                fused[((size_t)bb * L_ + r0 + row) * 128 + col] = b2f(sh) * cv;
            }
    }
}

// ---------------------------------------------------------------------------
extern "C" void kernel_launch(void* const* d_in, const int* in_sizes, int n_in,
                              void* d_out, int out_size, void* d_ws, size_t ws_size,
                              hipStream_t stream)
{
    const float* x      = (const float*)d_in[0];
    const float* hprev  = (const float*)d_in[1];
    const float* A_log  = (const float*)d_in[2];
    const float* Dp     = (const float*)d_in[3];
    const float* W_x    = (const float*)d_in[4];
    const float* W_dt   = (const float*)d_in[5];
    const float* b_dt   = (const float*)d_in[6];
    const float* conv_w = (const float*)d_in[7];
    const float* conv_b = (const float*)d_in[8];
    const float* W_f    = (const float*)d_in[9];
    const float* b_f    = (const float*)d_in[10];

    float* out   = (float*)d_out;                       // fused_output
    float* h_out = out + (size_t)BL * D_;               // h_t

    char* ws = (char*)d_ws;
    float* delta = (float*)ws;                  ws += (size_t)BL * 128 * 4;
    float* bcb   = (float*)ws;                  ws += (size_t)BL * 32 * 4;
    float* part  = (float*)ws;                  ws += (size_t)B_ * 128 * NC * 4;
    float* negAT = (float*)ws;                  ws += (size_t)N_ * 128 * 4;
    float* amaxb = (float*)ws;                  ws += (size_t)128 * 4;
    u16*   Wt0   = (u16*)ws;                    ws += (size_t)192 * 128 * 2;
    u16*   Wt2   = (u16*)ws;                    ws += (size_t)128 * 128 * 2;
    u16*   Wtc   = (u16*)ws;                    ws += (size_t)3 * 128 * 128 * 2;
    u16*   ssm   = (u16*)ws;

    prep_weff<<<dim3(32), dim3(512), 0, stream>>>(W_x, W_dt, Wt0);
    prep_rest<<<dim3(64, 7), dim3(256), 0, stream>>>(
        W_x, W_f, conv_w, A_log, Wt0, Wt2, Wtc, negAT, amaxb);
    gemm1<<<dim3(BL / 128), dim3(512), 0, stream>>>(
        x, Wt0, b_dt, delta, bcb, part);
    scan_prefix<<<dim3(B_, D_), dim3(512), 0, stream>>>(part);
    scan_main<<<dim3(SNC, B_), dim3(512), 0, stream>>>(
        delta, hprev, bcb, negAT, amaxb, Dp, part, Wt2, b_f, h_out, ssm);
    conv_fuse<<<dim3(L_ / 64, B_), dim3(512), 0, stream>>>(
        ssm, Wtc, conv_b, out);
}